// Round 1
// baseline (879.026 us; speedup 1.0000x reference)
//
#include <hip/hip_runtime.h>
#include <math.h>

#define NN 768
#define CS 384
#define CZ 128
#define CH 16
#define HH 12
#define PQ 4
#define PV 8
#define OUTIN 2112

#define SC_QK 0.14433756729740643f   // sqrt(1/(3*16))
#define SC_B  0.57735026918962576f   // sqrt(1/3)
#define SC_HW 0.13608276348795434f   // sqrt(2/(27*4))

// ---------------- Kernel A: input projections (s @ W.T + b) ----------------
// grid (96, 9), block 256. n-tile = 8, out-tile = 128 (1152 total outs).
__global__ __launch_bounds__(256) void kproj(
    const float* __restrict__ s,
    const float* __restrict__ Wq,  const float* __restrict__ bq,
    const float* __restrict__ Wkv, const float* __restrict__ bkv,
    const float* __restrict__ Wqp, const float* __restrict__ bqp,
    const float* __restrict__ Wkvp,const float* __restrict__ bkvp,
    float* __restrict__ q, float* __restrict__ kT, float* __restrict__ vT,
    float* __restrict__ qpr, float* __restrict__ kvpr)
{
    __shared__ float s_lds[8*384];
    int n0 = blockIdx.x * 8;
    int t = threadIdx.x;
    for (int idx = t; idx < 8*384; idx += 256)
        s_lds[idx] = s[(n0 + idx/384)*384 + (idx%384)];
    __syncthreads();

    int o = blockIdx.y * 128 + (t & 127);
    int ng = t >> 7;   // 0..1 -> 4 rows each
    const float* wrow; float bias;
    if (o < 192)      { wrow = Wq   + o*384;       bias = bq[o]; }
    else if (o < 576) { wrow = Wkv  + (o-192)*384; bias = bkv[o-192]; }
    else if (o < 720) { wrow = Wqp  + (o-576)*384; bias = bqp[o-576]; }
    else              { wrow = Wkvp + (o-720)*384; bias = bkvp[o-720]; }

    float acc[4] = {bias, bias, bias, bias};
    const float4* wr4 = reinterpret_cast<const float4*>(wrow);
    for (int c4 = 0; c4 < 96; ++c4) {
        float4 w = wr4[c4];
        #pragma unroll
        for (int nn = 0; nn < 4; ++nn) {
            const float* sr = &s_lds[(ng*4+nn)*384 + c4*4];
            acc[nn] = fmaf(w.x, sr[0], acc[nn]);
            acc[nn] = fmaf(w.y, sr[1], acc[nn]);
            acc[nn] = fmaf(w.z, sr[2], acc[nn]);
            acc[nn] = fmaf(w.w, sr[3], acc[nn]);
        }
    }
    #pragma unroll
    for (int nn = 0; nn < 4; ++nn) {
        int n = n0 + ng*4 + nn;
        float v = acc[nn];
        if (o < 192)      q[n*192 + o] = v;
        else if (o < 576) {
            int oo = o - 192, h = oo >> 5, cc = oo & 31;
            if (cc < 16) kT[(h*NN + n)*16 + cc] = v;
            else         vT[(h*NN + n)*16 + (cc-16)] = v;
        }
        else if (o < 720) qpr[n*144 + (o-576)] = v;
        else              kvpr[n*432 + (o-720)] = v;
    }
}

// ---------------- Kernel B: apply frames (rot, trans) to points ----------------
// grid 768, block 192 (one thread per point).
__global__ __launch_bounds__(192) void krot(
    const float* __restrict__ rot, const float* __restrict__ trans,
    const float* __restrict__ qpr, const float* __restrict__ kvpr,
    float* __restrict__ qp, float* __restrict__ kpT, float* __restrict__ vpT)
{
    int n = blockIdx.x;
    __shared__ float R[9], T[3];
    int t = threadIdx.x;
    if (t < 9) R[t] = rot[n*9 + t];
    if (t < 3) T[t] = trans[n*3 + t];
    __syncthreads();

    const float* src = (t < 48) ? (qpr + n*144 + t*3) : (kvpr + n*432 + (t-48)*3);
    float x = src[0], y = src[1], z = src[2];
    float wx = R[0]*x + R[1]*y + R[2]*z + T[0];
    float wy = R[3]*x + R[4]*y + R[5]*z + T[1];
    float wz = R[6]*x + R[7]*y + R[8]*z + T[2];
    if (t < 48) {
        float* d = qp + n*144 + t*3;
        d[0]=wx; d[1]=wy; d[2]=wz;
    } else {
        int pi = t - 48, h = pi/12, pp = pi%12;
        float* d = (pp < 4) ? (kpT + (h*NN+n)*12 + pp*3)
                            : (vpT + (h*NN+n)*24 + (pp-4)*3);
        d[0]=wx; d[1]=wy; d[2]=wz;
    }
}

// ---------------- Kernel C: fused attention (one block per query row i) ----------------
// 4 waves x 3 heads each; online softmax; z read streamed (phase1 bias, phase2 o_pair).
__global__ __launch_bounds__(256) void kattn(
    const float* __restrict__ z, const float* __restrict__ mask,
    const float* __restrict__ Wb, const float* __restrict__ bb,
    const float* __restrict__ head_w,
    const float* __restrict__ rot, const float* __restrict__ trans,
    const float* __restrict__ q, const float* __restrict__ kT, const float* __restrict__ vT,
    const float* __restrict__ qp, const float* __restrict__ kpT, const float* __restrict__ vpT,
    float* __restrict__ cat)
{
    __shared__ float q_lds[192], qp_lds[144], wb_lds[HH*128];
    __shared__ float hw_lds[HH], bb_lds[HH], R[9], T[3];
    __shared__ float opt_lds[HH][24];

    int i = blockIdx.x;
    int t = threadIdx.x;
    for (int idx = t; idx < 192;  idx += 256) q_lds[idx]  = q[i*192 + idx];
    for (int idx = t; idx < 144;  idx += 256) qp_lds[idx] = qp[i*144 + idx];
    for (int idx = t; idx < 1536; idx += 256) wb_lds[idx] = Wb[idx];
    if (t < HH) { hw_lds[t] = log1pf(expf(head_w[t])) * SC_HW; bb_lds[t] = bb[t]; }
    if (t < 9) R[t] = rot[i*9 + t];
    if (t < 3) T[t] = trans[i*3 + t];
    __syncthreads();

    int w = t >> 6, l = t & 63;
    int h0 = w*3;
    float maski = mask[i];

    float m_run[3] = {-1e30f,-1e30f,-1e30f};
    float l_run[3] = {0.f,0.f,0.f};
    float op0[3] = {0.f,0.f,0.f}, op1[3] = {0.f,0.f,0.f}, ov[3] = {0.f,0.f,0.f};
    float hwv[3], bbv[3];
    #pragma unroll
    for (int hi = 0; hi < 3; ++hi) { hwv[hi] = hw_lds[h0+hi]; bbv[hi] = bb_lds[h0+hi]; }

    for (int j0 = 0; j0 < NN; j0 += 64) {
        __syncthreads();   // keep waves loosely synced for L1 locality on z
        int j = j0 + l;
        // ---- phase 1: logits for my 3 heads at column j ----
        float biasv[3] = {bbv[0], bbv[1], bbv[2]};
        const float4* zr = reinterpret_cast<const float4*>(z + ((size_t)i*NN + j)*CZ);
        #pragma unroll 8
        for (int c4 = 0; c4 < 32; ++c4) {
            float4 zq = zr[c4];
            #pragma unroll
            for (int hi = 0; hi < 3; ++hi) {
                float4 wq = reinterpret_cast<const float4*>(wb_lds + (h0+hi)*128)[c4];
                biasv[hi] += zq.x*wq.x + zq.y*wq.y + zq.z*wq.z + zq.w*wq.w;
            }
        }
        float pbuf[3];
        float mterm = 1e9f * (maski * mask[j] - 1.0f);
        #pragma unroll
        for (int hi = 0; hi < 3; ++hi) {
            int hh = h0 + hi;
            float qk = 0.f;
            const float4* kr = reinterpret_cast<const float4*>(kT + ((size_t)(hh*NN + j) << 4));
            const float4* qr = reinterpret_cast<const float4*>(q_lds + hh*16);
            #pragma unroll
            for (int c4 = 0; c4 < 4; ++c4) {
                float4 kq = kr[c4], qq = qr[c4];
                qk += kq.x*qq.x + kq.y*qq.y + kq.z*qq.z + kq.w*qq.w;
            }
            float d2 = 0.f;
            const float* kp  = kpT + (size_t)(hh*NN + j)*12;
            const float* qpv = qp_lds + hh*12;
            #pragma unroll
            for (int e = 0; e < 12; ++e) { float df = qpv[e] - kp[e]; d2 = fmaf(df, df, d2); }
            float logit = fmaf(qk, SC_QK, fmaf(biasv[hi], SC_B, -0.5f*hwv[hi]*d2)) + mterm;

            // ---- online softmax update (wave-wide) ----
            float tmax = logit;
            #pragma unroll
            for (int off = 32; off >= 1; off >>= 1) tmax = fmaxf(tmax, __shfl_xor(tmax, off, 64));
            float mnew = fmaxf(m_run[hi], tmax);
            float corr = __expf(m_run[hi] - mnew);
            float p    = __expf(logit - mnew);
            float tsum = p;
            #pragma unroll
            for (int off = 32; off >= 1; off >>= 1) tsum += __shfl_xor(tsum, off, 64);
            l_run[hi] = l_run[hi]*corr + tsum;
            m_run[hi] = mnew;
            op0[hi] *= corr; op1[hi] *= corr; ov[hi] *= corr;
            pbuf[hi] = p;
        }
        // ---- phase 2: accumulate o_pair / o / o_pt over this tile ----
        const float* zbase = z + ((size_t)i*NN + j0)*CZ;
        for (int jl = 0; jl < 64; ++jl) {
            int jj = j0 + jl;
            float p0 = __shfl(pbuf[0], jl, 64);
            float p1 = __shfl(pbuf[1], jl, 64);
            float p2 = __shfl(pbuf[2], jl, 64);
            const float* zrow = zbase + (size_t)jl*CZ;
            float z0 = zrow[l], z1 = zrow[64 + l];
            op0[0] = fmaf(p0, z0, op0[0]); op1[0] = fmaf(p0, z1, op1[0]);
            op0[1] = fmaf(p1, z0, op0[1]); op1[1] = fmaf(p1, z1, op1[1]);
            op0[2] = fmaf(p2, z0, op0[2]); op1[2] = fmaf(p2, z1, op1[2]);
            if (l < 16) {
                ov[0] = fmaf(p0, vT[(size_t)((h0+0)*NN + jj)*16 + l], ov[0]);
                ov[1] = fmaf(p1, vT[(size_t)((h0+1)*NN + jj)*16 + l], ov[1]);
                ov[2] = fmaf(p2, vT[(size_t)((h0+2)*NN + jj)*16 + l], ov[2]);
            } else if (l < 40) {
                int e = l - 16;
                ov[0] = fmaf(p0, vpT[(size_t)((h0+0)*NN + jj)*24 + e], ov[0]);
                ov[1] = fmaf(p1, vpT[(size_t)((h0+1)*NN + jj)*24 + e], ov[1]);
                ov[2] = fmaf(p2, vpT[(size_t)((h0+2)*NN + jj)*24 + e], ov[2]);
            }
        }
    }

    // ---- finalize ----
    float* crow = cat + (size_t)i * OUTIN;
    #pragma unroll
    for (int hi = 0; hi < 3; ++hi) {
        float inv = 1.0f / l_run[hi];
        int hh = h0 + hi;
        crow[576 + hh*128 + l]      = op0[hi]*inv;
        crow[576 + hh*128 + 64 + l] = op1[hi]*inv;
        if (l < 16)      crow[hh*16 + l] = ov[hi]*inv;
        else if (l < 40) opt_lds[hh][l-16] = ov[hi]*inv;   // world-frame o_pt
    }
    __syncthreads();
    #pragma unroll
    for (int hi = 0; hi < 3; ++hi) {
        int hh = h0 + hi;
        if (l < 24) {                 // local coords: x = sum_y R[y][x]*(w[y]-T[y])
            int p = l/3, x = l%3;
            float lx = R[0*3+x]*(opt_lds[hh][p*3+0]-T[0])
                     + R[1*3+x]*(opt_lds[hh][p*3+1]-T[1])
                     + R[2*3+x]*(opt_lds[hh][p*3+2]-T[2]);
            crow[192 + x*96 + hh*8 + p] = lx;
        } else if (l < 32) {          // norms (rotation-invariant)
            int p = l - 24;
            float dx = opt_lds[hh][p*3+0]-T[0];
            float dy = opt_lds[hh][p*3+1]-T[1];
            float dz = opt_lds[hh][p*3+2]-T[2];
            crow[480 + hh*8 + p] = sqrtf(fmaf(dx,dx,fmaf(dy,dy,dz*dz)) + 1e-8f);
        }
    }
}

// ---------------- Kernel D: output projection (cat @ Wout.T + bout) ----------------
// grid (96, 3), block 256. K = 2112 in 4 chunks of 528.
__global__ __launch_bounds__(256) void kout(
    const float* __restrict__ cat, const float* __restrict__ Wout,
    const float* __restrict__ bout, float* __restrict__ out)
{
    __shared__ float c_lds[8*528];
    int n0 = blockIdx.x * 8;
    int t = threadIdx.x;
    int o = blockIdx.y * 128 + (t & 127);
    int ng = t >> 7;
    float b = bout[o];
    float acc[4] = {b, b, b, b};
    for (int ch = 0; ch < 4; ++ch) {
        __syncthreads();
        for (int idx = t; idx < 8*528; idx += 256)
            c_lds[idx] = cat[(size_t)(n0 + idx/528)*OUTIN + ch*528 + (idx%528)];
        __syncthreads();
        const float4* wr = reinterpret_cast<const float4*>(Wout + (size_t)o*OUTIN + ch*528);
        for (int c4 = 0; c4 < 132; ++c4) {
            float4 wv = wr[c4];
            #pragma unroll
            for (int nn = 0; nn < 4; ++nn) {
                const float* cr = &c_lds[(ng*4+nn)*528 + c4*4];
                acc[nn] = fmaf(wv.x, cr[0], acc[nn]);
                acc[nn] = fmaf(wv.y, cr[1], acc[nn]);
                acc[nn] = fmaf(wv.z, cr[2], acc[nn]);
                acc[nn] = fmaf(wv.w, cr[3], acc[nn]);
            }
        }
    }
    #pragma unroll
    for (int nn = 0; nn < 4; ++nn)
        out[(size_t)(n0 + ng*4 + nn)*384 + o] = acc[nn];
}

extern "C" void kernel_launch(void* const* d_in, const int* in_sizes, int n_in,
                              void* d_out, int out_size, void* d_ws, size_t ws_size,
                              hipStream_t stream) {
    const float* s      = (const float*)d_in[0];
    const float* z      = (const float*)d_in[1];
    const float* rot    = (const float*)d_in[2];
    const float* trans  = (const float*)d_in[3];
    const float* mask   = (const float*)d_in[4];
    const float* Wq     = (const float*)d_in[5];
    const float* bq     = (const float*)d_in[6];
    const float* Wkv    = (const float*)d_in[7];
    const float* bkv    = (const float*)d_in[8];
    const float* Wqp    = (const float*)d_in[9];
    const float* bqp    = (const float*)d_in[10];
    const float* Wkvp   = (const float*)d_in[11];
    const float* bkvp   = (const float*)d_in[12];
    const float* Wb     = (const float*)d_in[13];
    const float* bb     = (const float*)d_in[14];
    const float* head_w = (const float*)d_in[15];
    const float* Wout   = (const float*)d_in[16];
    const float* bout   = (const float*)d_in[17];
    float* out = (float*)d_out;
    float* ws  = (float*)d_ws;

    float* q    = ws;             // 768*192
    float* kT   = ws + 147456;    // [12][768][16]
    float* vT   = ws + 294912;    // [12][768][16]
    float* qp   = ws + 442368;    // [768][144] world
    float* kpT  = ws + 552960;    // [12][768][12]
    float* vpT  = ws + 663552;    // [12][768][24]
    float* qpr  = ws + 884736;    // raw q_pts
    float* kvpr = ws + 995328;    // raw kv_pts
    float* cat  = ws + 1327104;   // [768][2112]

    kproj<<<dim3(96, 9), 256, 0, stream>>>(s, Wq, bq, Wkv, bkv, Wqp, bqp, Wkvp, bkvp,
                                           q, kT, vT, qpr, kvpr);
    krot<<<dim3(768), 192, 0, stream>>>(rot, trans, qpr, kvpr, qp, kpT, vpT);
    kattn<<<dim3(768), 256, 0, stream>>>(z, mask, Wb, bb, head_w, rot, trans,
                                         q, kT, vT, qp, kpT, vpT, cat);
    kout<<<dim3(96, 3), 256, 0, stream>>>(cat, Wout, bout, out);
}